// Round 8
// baseline (123.373 us; speedup 1.0000x reference)
//
#include <hip/hip_runtime.h>
#include <stdint.h>

#define EMBED 384
#define NHEAD 6
#define HSZ   64
#define BATCH 32
#define SEQ   768
#define MROWS (BATCH * SEQ)   // 24576
#define NTILE (SEQ / 64)      // 12

typedef __bf16 bf16x8 __attribute__((ext_vector_type(8)));
typedef float  f32x4  __attribute__((ext_vector_type(4)));
typedef float  f32x16 __attribute__((ext_vector_type(16)));

#define GLD16(gp, lp)                                                        \
  __builtin_amdgcn_global_load_lds(                                          \
      (const __attribute__((address_space(1))) void*)(gp),                   \
      (__attribute__((address_space(3))) void*)(lp), 16, 0, 0)

__device__ inline unsigned short nbf(float f) {   // native RNE convert
  union { __bf16 b; unsigned short s; } c; c.b = (__bf16)f; return c.s;
}
__device__ inline uint32_t pk2(float a, float b) { // -> v_cvt_pk_bf16_f32
  union { __bf16 b[2]; uint32_t u; } c;
  c.b[0] = (__bf16)a; c.b[1] = (__bf16)b; return c.u;
}

// ---------------- fused fp32 -> bf16 convert: X then Wq|Wk|Wv|Wo ------------
__global__ __launch_bounds__(256) void cvtAll(const float* __restrict__ X,
                                              const float* __restrict__ Wq,
                                              const float* __restrict__ Wk,
                                              const float* __restrict__ Wv,
                                              const float* __restrict__ Wo,
                                              unsigned short* __restrict__ dstW,
                                              unsigned short* __restrict__ dstX) {
  const int NX = MROWS * EMBED, NW = EMBED * EMBED;
  int i = (blockIdx.x * 256 + threadIdx.x) * 4;
  const float* src;
  unsigned short* dst;
  if (i < NX) {
    src = X + i; dst = dstX + i;
  } else {
    int j = i - NX;
    int wsel = j / NW, r = j - wsel * NW;
    src = ((wsel == 0) ? Wq : (wsel == 1) ? Wk : (wsel == 2) ? Wv : Wo) + r;
    dst = dstW + j;
  }
  float4 v = *reinterpret_cast<const float4*>(src);
  uint2 o;
  o.x = pk2(v.x, v.y); o.y = pk2(v.z, v.w);
  *reinterpret_cast<uint2*>(dst) = o;
}

// ---------------- GEMM: C[m,n] = sum_k A[m,k] * B[n,k]  (B stored [N][K]) ----
// 2-phase double-buffered global_load_lds staging (1 barrier per K-step).
// MODE 0: scatters Q/K bf16 (Q scaled 0.125); V written transposed VT[bh][d][t].
// MODE 1: fp32 out + bias.
template <int MODE>
__global__ __launch_bounds__(256) void gemm_bt(
    const unsigned short* __restrict__ Ab,
    const unsigned short* __restrict__ Bw,
    unsigned short* __restrict__ Qb,
    unsigned short* __restrict__ Kb,
    unsigned short* __restrict__ VT,
    float* __restrict__ Co,
    const float* __restrict__ bias) {
  __shared__ __align__(16) short SH[32768];   // 64KB: 2 bufs x (A 16KB + B 16KB)
  const int tid = threadIdx.x;
  const int lane = tid & 63;
  const int w = tid >> 6;
  const int wm = w >> 1, wn = w & 1;
  const int m0 = blockIdx.x * 128, n0 = blockIdx.y * 128;
  const int l15 = lane & 15, lg = lane >> 4;
  char* shc = (char*)SH;

  auto stage = [&](int kt, int buf) {
    short* At = SH + buf * 16384;
    short* Bt = At + 8192;
    const int k0 = kt * 64;
#pragma unroll
    for (int j = 0; j < 4; ++j) {
      const int u = j * 256 + tid;
      const int row = u >> 3, un = u & 7;
      const int sw = (un ^ (row & 7)) * 8;
      const int ub = (j * 256 + (tid & ~63)) * 8;
      GLD16(Ab + (size_t)(m0 + row) * EMBED + k0 + sw, At + ub);
      GLD16(Bw + (size_t)(n0 + row) * EMBED + k0 + sw, Bt + ub);
    }
  };

  f32x4 acc[4][4];
#pragma unroll
  for (int i = 0; i < 4; ++i)
#pragma unroll
    for (int j = 0; j < 4; ++j) acc[i][j] = f32x4{0.f, 0.f, 0.f, 0.f};

  stage(0, 0);
  int cur = 0;
#pragma unroll 1
  for (int kt = 0; kt < 6; ++kt) {
    __syncthreads();                        // drains stage(kt) [vmcnt(0) auto]
    if (kt < 5) stage(kt + 1, cur ^ 1);     // next-tile loads fly under MFMA
    const char* Ac = shc + cur * 32768;
    const char* Bc = Ac + 16384;
#pragma unroll
    for (int kc = 0; kc < 2; ++kc) {
      bf16x8 af[4], bfr[4];
#pragma unroll
      for (int mt = 0; mt < 4; ++mt) {
        const int row = wm * 64 + mt * 16 + l15;
        af[mt] = *(const bf16x8*)(Ac + row * 128 + (((kc * 4 + lg) ^ (row & 7)) * 16));
      }
#pragma unroll
      for (int nt = 0; nt < 4; ++nt) {
        const int row = wn * 64 + nt * 16 + l15;
        bfr[nt] = *(const bf16x8*)(Bc + row * 128 + (((kc * 4 + lg) ^ (row & 7)) * 16));
      }
#pragma unroll
      for (int mt = 0; mt < 4; ++mt)
#pragma unroll
        for (int nt = 0; nt < 4; ++nt)
          acc[mt][nt] = __builtin_amdgcn_mfma_f32_16x16x32_bf16(
              af[mt], bfr[nt], acc[mt][nt], 0, 0, 0);
    }
    cur ^= 1;
  }

  if (MODE == 0 && n0 >= 768) {
    // ---- V blocks: transpose via LDS (reuse buf0, 32KB), write VT coalesced --
    const int b = m0 / SEQ, t0 = m0 - b * SEQ;
    __syncthreads();
#pragma unroll
    for (int mt = 0; mt < 4; ++mt)
#pragma unroll
      for (int nt = 0; nt < 4; ++nt)
#pragma unroll
        for (int r = 0; r < 4; ++r) {
          const int tl = wm * 64 + mt * 16 + lg * 4 + r;
          const int nl = wn * 64 + nt * 16 + l15;
          *(unsigned short*)(shc + nl * 256 + (((tl >> 3) ^ (nl & 7)) * 16) +
                             (tl & 7) * 2) = nbf(acc[mt][nt][r]);
        }
    __syncthreads();
#pragma unroll
    for (int j = 0; j < 8; ++j) {
      const int u = j * 256 + tid;
      const int row = u >> 4, un = u & 15;
      int4 vv = *(const int4*)(shc + row * 256 + ((un ^ (row & 7)) * 16));
      const int cg = (n0 - 768) + row;
      const int h = cg >> 6, d = cg & 63;
      *(int4*)(VT + ((size_t)(b * NHEAD + h) * HSZ + d) * SEQ + t0 + un * 8) = vv;
    }
    return;
  }

#pragma unroll
  for (int mt = 0; mt < 4; ++mt) {
#pragma unroll
    for (int nt = 0; nt < 4; ++nt) {
#pragma unroll
      for (int r = 0; r < 4; ++r) {
        const int m = m0 + wm * 64 + mt * 16 + lg * 4 + r;
        const int n = n0 + wn * 64 + nt * 16 + l15;
        const float v = acc[mt][nt][r];
        if (MODE == 0) {
          const int which = n / EMBED;   // 0=Q, 1=K here (V handled above)
          const int c = n - which * EMBED;
          const int h = c >> 6, d = c & 63;
          const int b = m / SEQ, t = m - b * SEQ;
          const size_t off = ((size_t)((b * NHEAD + h) * SEQ + t)) * HSZ + d;
          unsigned short* dstp = (which == 0) ? Qb : Kb;
          dstp[off] = nbf(which == 0 ? v * 0.125f : v);  // fold 1/sqrt(D) into Q
        } else {
          Co[(size_t)m * EMBED + n] = v + bias[n];
        }
      }
    }
  }
}

// ---------------- flash attention, causal, 32x32 MFMA, P-in-register ---------
// grid (8, 144): bh = (by/6)*8+bx groups same-bh blocks on one XCD.
// 4 waves x 32 q-rows (16 from tile qtA + 16 from tile qtB per lane-column).
// Lane owns ONE q (col = lane&31); lane and lane+32 split the 64 kv rows.
// P redistributed lane-half<->lane-half via v_permlane32_swap_b32 (no LDS).
__global__ __launch_bounds__(256, 3) void attn(const unsigned short* __restrict__ Qb,
                                               const unsigned short* __restrict__ Kb,
                                               const unsigned short* __restrict__ VT,
                                               unsigned short* __restrict__ AO) {
  __shared__ __align__(16) short Kt[2][64 * 64];   // [kv][d] swizzled, dbuf
  __shared__ __align__(16) short Vt[2][64 * 64];   // [d][kv] swizzled, dbuf
  const int tid = threadIdx.x, lane = tid & 63, w = tid >> 6;
  const int l31 = lane & 31, hi = lane >> 5;
  const int bh = (blockIdx.y / 6) * 8 + blockIdx.x;
  const int qtA = blockIdx.y % 6, qtB = (NTILE - 1) - qtA;
  const size_t base = (size_t)bh * SEQ * HSZ;      // Qb/Kb [bh][t][d]

  // this lane's single q row (cols 0-15 -> tile A, cols 16-31 -> tile B)
  const int qloc = w * 16 + (l31 & 15);
  const int q = ((l31 < 16) ? qtA * 64 : qtB * 64) + qloc;

  // Q fragment: full 64-d row; B-operand k = kc*16 + hi*8 + i
  bf16x8 qf[4];
#pragma unroll
  for (int kc = 0; kc < 4; ++kc)
    qf[kc] = *(const bf16x8*)(Qb + base + (size_t)q * HSZ + kc * 16 + hi * 8);

  f32x16 o0, o1;                 // O^T[d][q]: d-tiles 0-31, 32-63
#pragma unroll
  for (int r = 0; r < 16; ++r) { o0[r] = 0.f; o1[r] = 0.f; }
  float m = -1.0e30f, l = 0.f;   // l = per-lane partial (combined in epilogue)

  auto stage = [&](int kt, int buf) {
#pragma unroll
    for (int j = 0; j < 2; ++j) {
      const int u = j * 256 + tid;
      const int row = u >> 3, un = u & 7;
      const int sw = (un ^ (row & 7)) * 8;
      const int ub = (j * 256 + (tid & ~63)) * 8;
      GLD16(Kb + base + (size_t)(kt * 64 + row) * HSZ + sw, &Kt[buf][ub]);
      GLD16(VT + base + (size_t)row * SEQ + kt * 64 + sw, &Vt[buf][ub]);
    }
  };

  stage(0, 0);
  int cur = 0;
#pragma unroll 1
  for (int kt = 0; kt <= qtB; ++kt) {
    __syncthreads();                        // buf[cur] staged; buf[cur^1] free
    if (kt < qtB) stage(kt + 1, cur ^ 1);   // next-tile loads fly under compute
    const char* Kc = (const char*)Kt[cur];
    const char* Vc = (const char*)Vt[cur];
    const int kv0 = kt * 64;

    // ---- S^T = K x Q^T : two 32x32 kv-tiles, 4 k-steps of 16 ----
    f32x16 s0, s1;
#pragma unroll
    for (int r = 0; r < 16; ++r) { s0[r] = 0.f; s1[r] = 0.f; }
    __builtin_amdgcn_s_setprio(1);
#pragma unroll
    for (int kc = 0; kc < 4; ++kc) {
      const int un = ((kc * 2 + hi) ^ (l31 & 7)) * 16;
      bf16x8 kf0 = *(const bf16x8*)(Kc + l31 * 128 + un);
      bf16x8 kf1 = *(const bf16x8*)(Kc + (32 + l31) * 128 + un);
      s0 = __builtin_amdgcn_mfma_f32_32x32x16_bf16(kf0, qf[kc], s0, 0, 0, 0);
      s1 = __builtin_amdgcn_mfma_f32_32x32x16_bf16(kf1, qf[kc], s1, 0, 0, 0);
    }
    __builtin_amdgcn_s_setprio(0);

    // ---- causal mask (wave-uniform gate; covers diag + dead-A iterations) ---
    if (kt >= qtA) {
#pragma unroll
      for (int r = 0; r < 16; ++r) {
        const int kvr = kv0 + (r & 3) + 8 * (r >> 2) + 4 * hi;
        if (kvr > q) s0[r] = -3.0e38f;
        if (kvr + 32 > q) s1[r] = -3.0e38f;
      }
    }

    // ---- online softmax: row split across lane/lane+32 -> 1 shfl ----
    float ma = fmaxf(s0[0], s1[0]), mb = fmaxf(s0[1], s1[1]);
    float mc = fmaxf(s0[2], s1[2]), md = fmaxf(s0[3], s1[3]);
#pragma unroll
    for (int r = 4; r < 16; r += 4) {
      ma = fmaxf(ma, fmaxf(s0[r], s1[r]));
      mb = fmaxf(mb, fmaxf(s0[r + 1], s1[r + 1]));
      mc = fmaxf(mc, fmaxf(s0[r + 2], s1[r + 2]));
      md = fmaxf(md, fmaxf(s0[r + 3], s1[r + 3]));
    }
    float mx = fmaxf(fmaxf(ma, mb), fmaxf(mc, md));
    mx = fmaxf(mx, __shfl_xor(mx, 32, 64));
    const float mn = fmaxf(m, mx);
    const float alpha = __expf(m - mn);
    m = mn;
    float sr0 = 0.f, sr1 = 0.f, sr2 = 0.f, sr3 = 0.f;
#pragma unroll
    for (int r = 0; r < 16; r += 4) {
      s0[r] = __expf(s0[r] - mn);     s1[r] = __expf(s1[r] - mn);
      s0[r + 1] = __expf(s0[r + 1] - mn); s1[r + 1] = __expf(s1[r + 1] - mn);
      s0[r + 2] = __expf(s0[r + 2] - mn); s1[r + 2] = __expf(s1[r + 2] - mn);
      s0[r + 3] = __expf(s0[r + 3] - mn); s1[r + 3] = __expf(s1[r + 3] - mn);
      sr0 += s0[r] + s1[r];
      sr1 += s0[r + 1] + s1[r + 1];
      sr2 += s0[r + 2] + s1[r + 2];
      sr3 += s0[r + 3] + s1[r + 3];
    }
    l = l * alpha + ((sr0 + sr1) + (sr2 + sr3));
#pragma unroll
    for (int r = 0; r < 16; ++r) { o0[r] *= alpha; o1[r] *= alpha; }

    // ---- P -> bf16 B-fragments via permlane32_swap (in-register, no LDS) ----
    // chunk ks (kv16): frag k = hi*8+i; own quads at local kv {4hi..}, {8+4hi..}
    bf16x8 pf[4];
#pragma unroll
    for (int ks = 0; ks < 4; ++ks) {
      const int j = ks & 1;
      uint32_t a0, a1, b0, b1;
      if (ks < 2) {
        a0 = pk2(s0[8 * j + 0], s0[8 * j + 1]);
        a1 = pk2(s0[8 * j + 2], s0[8 * j + 3]);
        b0 = pk2(s0[8 * j + 4], s0[8 * j + 5]);
        b1 = pk2(s0[8 * j + 6], s0[8 * j + 7]);
      } else {
        a0 = pk2(s1[8 * j + 0], s1[8 * j + 1]);
        a1 = pk2(s1[8 * j + 2], s1[8 * j + 3]);
        b0 = pk2(s1[8 * j + 4], s1[8 * j + 5]);
        b1 = pk2(s1[8 * j + 6], s1[8 * j + 7]);
      }
      asm volatile("v_permlane32_swap_b32 %0, %1" : "+v"(a0), "+v"(b0));
      asm volatile("v_permlane32_swap_b32 %0, %1" : "+v"(a1), "+v"(b1));
      union { uint32_t u[4]; bf16x8 v; } cv;
      cv.u[0] = a0; cv.u[1] = a1; cv.u[2] = b0; cv.u[3] = b1;
      pf[ks] = cv.v;
    }

    // ---- O^T += V^T x P : two 32-d tiles, 4 kv-steps of 16 ----
    __builtin_amdgcn_s_setprio(1);
#pragma unroll
    for (int ks = 0; ks < 4; ++ks) {
      const int un = ((ks * 2 + hi) ^ (l31 & 7)) * 16;
      bf16x8 vf0 = *(const bf16x8*)(Vc + l31 * 128 + un);
      bf16x8 vf1 = *(const bf16x8*)(Vc + (32 + l31) * 128 + un);
      o0 = __builtin_amdgcn_mfma_f32_32x32x16_bf16(vf0, pf[ks], o0, 0, 0, 0);
      o1 = __builtin_amdgcn_mfma_f32_32x32x16_bf16(vf1, pf[ks], o1, 0, 0, 0);
    }
    __builtin_amdgcn_s_setprio(0);
    cur ^= 1;
  }

  // ---- epilogue: combine l halves; store O[q][d] as 8B groups ----
  float lt = l + __shfl_xor(l, 32, 64);
  const float inv = 1.f / lt;
  const int bq = bh / NHEAD, h = bh - bq * NHEAD;
  unsigned short* orow = AO + (size_t)(bq * SEQ + q) * EMBED + h * HSZ;
#pragma unroll
  for (int rq = 0; rq < 4; ++rq) {
    ushort4 st0, st1;
    st0.x = nbf(o0[rq * 4 + 0] * inv); st0.y = nbf(o0[rq * 4 + 1] * inv);
    st0.z = nbf(o0[rq * 4 + 2] * inv); st0.w = nbf(o0[rq * 4 + 3] * inv);
    st1.x = nbf(o1[rq * 4 + 0] * inv); st1.y = nbf(o1[rq * 4 + 1] * inv);
    st1.z = nbf(o1[rq * 4 + 2] * inv); st1.w = nbf(o1[rq * 4 + 3] * inv);
    const int d = rq * 8 + hi * 4;
    *(ushort4*)(orow + d) = st0;
    *(ushort4*)(orow + 32 + d) = st1;
  }
}

extern "C" void kernel_launch(void* const* d_in, const int* in_sizes, int n_in,
                              void* d_out, int out_size, void* d_ws, size_t ws_size,
                              hipStream_t stream) {
  const float* X  = (const float*)d_in[0];
  const float* Wq = (const float*)d_in[1];
  const float* Wk = (const float*)d_in[2];
  const float* Wv = (const float*)d_in[3];
  const float* Wo = (const float*)d_in[4];
  const float* bo = (const float*)d_in[5];
  float* out = (float*)d_out;

  const size_t NW = (size_t)EMBED * EMBED;   // 147456
  const size_t NX = (size_t)MROWS * EMBED;   // 9437184
  unsigned short* ws    = (unsigned short*)d_ws;
  unsigned short* Wqkvb = ws;                // 3*NW
  unsigned short* Wob   = Wqkvb + 3 * NW;    // NW (contiguous after Wqkvb)
  unsigned short* XbAO  = Wob + NW;          // NX: Xb (pre-attn) then AO
  unsigned short* Qb    = XbAO + NX;         // NX  [B,H,T,D]
  unsigned short* Kb    = Qb + NX;           // NX  [B,H,T,D]
  unsigned short* VTb   = Kb + NX;           // NX  [B,H,D,T] (transposed V)
  // total: 4*NW + 4*NX ushorts = 76.7 MB of d_ws

  cvtAll<<<(int)((NX + 4 * NW) / 4 / 256), 256, 0, stream>>>(
      X, Wq, Wk, Wv, Wo, Wqkvb, XbAO);

  gemm_bt<0><<<dim3(MROWS / 128, (3 * EMBED) / 128), 256, 0, stream>>>(
      XbAO, Wqkvb, Qb, Kb, VTb, nullptr, nullptr);

  attn<<<dim3(8, 144), 256, 0, stream>>>(Qb, Kb, VTb, XbAO);

  gemm_bt<1><<<dim3(MROWS / 128, EMBED / 128), 256, 0, stream>>>(
      XbAO, Wob, nullptr, nullptr, nullptr, out, bo);
}

// Round 9
// 110.013 us; speedup vs baseline: 1.1214x; 1.1214x over previous
//
#include <hip/hip_runtime.h>
#include <stdint.h>

#define EMBED 384
#define NHEAD 6
#define HSZ   64
#define BATCH 32
#define SEQ   768
#define MROWS (BATCH * SEQ)   // 24576
#define NTILE (SEQ / 64)      // 12

typedef __bf16 bf16x8 __attribute__((ext_vector_type(8)));
typedef float  f32x4  __attribute__((ext_vector_type(4)));

#define GLD16(gp, lp)                                                        \
  __builtin_amdgcn_global_load_lds(                                          \
      (const __attribute__((address_space(1))) void*)(gp),                   \
      (__attribute__((address_space(3))) void*)(lp), 16, 0, 0)

__device__ inline unsigned short nbf(float f) {   // native RNE convert
  union { __bf16 b; unsigned short s; } c; c.b = (__bf16)f; return c.s;
}
__device__ inline uint32_t pk2(float a, float b) { // -> v_cvt_pk_bf16_f32
  union { __bf16 b[2]; uint32_t u; } c;
  c.b[0] = (__bf16)a; c.b[1] = (__bf16)b; return c.u;
}

// ---------------- fused fp32 -> bf16 convert: X then Wq|Wk|Wv|Wo ------------
__global__ __launch_bounds__(256) void cvtAll(const float* __restrict__ X,
                                              const float* __restrict__ Wq,
                                              const float* __restrict__ Wk,
                                              const float* __restrict__ Wv,
                                              const float* __restrict__ Wo,
                                              unsigned short* __restrict__ dstW,
                                              unsigned short* __restrict__ dstX) {
  const int NX = MROWS * EMBED, NW = EMBED * EMBED;
  int i = (blockIdx.x * 256 + threadIdx.x) * 4;
  const float* src;
  unsigned short* dst;
  if (i < NX) {
    src = X + i; dst = dstX + i;
  } else {
    int j = i - NX;
    int wsel = j / NW, r = j - wsel * NW;
    src = ((wsel == 0) ? Wq : (wsel == 1) ? Wk : (wsel == 2) ? Wv : Wo) + r;
    dst = dstW + j;
  }
  float4 v = *reinterpret_cast<const float4*>(src);
  uint2 o;
  o.x = pk2(v.x, v.y); o.y = pk2(v.z, v.w);
  *reinterpret_cast<uint2*>(dst) = o;
}

// ---------------- GEMM: C[m,n] = sum_k A[m,k] * B[n,k]  (B stored [N][K]) ----
// 2-phase double-buffered global_load_lds staging (1 barrier per K-step).
// MODE 0: BM=192, 6 waves; scatters Q/K bf16 (Q scaled 0.125); V transposed
//         to VT[bh][d][t]. MODE 1: BM=128, 4 waves; fp32 out + bias.
template <int MODE>
__global__ __launch_bounds__(MODE == 0 ? 384 : 256, MODE == 0 ? 3 : 2)
void gemm_bt(
    const unsigned short* __restrict__ Ab,
    const unsigned short* __restrict__ Bw,
    unsigned short* __restrict__ Qb,
    unsigned short* __restrict__ Kb,
    unsigned short* __restrict__ VT,
    float* __restrict__ Co,
    const float* __restrict__ bias) {
  constexpr int BM = (MODE == 0) ? 192 : 128;
  constexpr int THREADS = (MODE == 0) ? 384 : 256;
  constexpr int BUFSZ = BM * 64 + 8192;            // shorts per buffer (A+B)
  constexpr int BUNITS = 1024;                     // B: 128 rows x 8 units
  constexpr int BPASS = (BUNITS + THREADS - 1) / THREADS;
  __shared__ __align__(16) short SH[2 * BUFSZ];
  const int tid = threadIdx.x;
  const int lane = tid & 63;
  const int w = tid >> 6;
  const int wm = w >> 1, wn = w & 1;               // waves: (BM/64) x 2 of 64x64
  const int m0 = blockIdx.x * BM, n0 = blockIdx.y * 128;
  const int l15 = lane & 15, lg = lane >> 4;

  auto stage = [&](int kt, int buf) {
    short* At = SH + buf * BUFSZ;
    short* Bt = At + BM * 64;
    const int k0 = kt * 64;
#pragma unroll
    for (int j = 0; j < 4; ++j) {                  // A: BM*8/THREADS == 4
      const int u = j * THREADS + tid, row = u >> 3, un = u & 7;
      GLD16(Ab + (size_t)(m0 + row) * EMBED + k0 + ((un ^ (row & 7)) * 8),
            At + (j * THREADS + (tid & ~63)) * 8);
    }
#pragma unroll
    for (int j = 0; j < BPASS; ++j) {
      const int u = j * THREADS + tid;
      if (THREADS * BPASS == BUNITS || u < BUNITS) {
        const int row = u >> 3, un = u & 7;
        GLD16(Bw + (size_t)(n0 + row) * EMBED + k0 + ((un ^ (row & 7)) * 8),
              Bt + (j * THREADS + (tid & ~63)) * 8);
      }
    }
  };

  f32x4 acc[4][4];
#pragma unroll
  for (int i = 0; i < 4; ++i)
#pragma unroll
    for (int j = 0; j < 4; ++j) acc[i][j] = f32x4{0.f, 0.f, 0.f, 0.f};

  stage(0, 0);
  int cur = 0;
#pragma unroll 1
  for (int kt = 0; kt < 6; ++kt) {
    __syncthreads();                        // drains stage(kt) [vmcnt(0) auto]
    if (kt < 5) stage(kt + 1, cur ^ 1);     // next-tile loads fly under MFMA
    const char* Ac = (const char*)(SH + cur * BUFSZ);
    const char* Bc = Ac + BM * 128;         // BM*64 shorts
#pragma unroll
    for (int kc = 0; kc < 2; ++kc) {
      bf16x8 af[4], bfr[4];
#pragma unroll
      for (int mt = 0; mt < 4; ++mt) {
        const int row = wm * 64 + mt * 16 + l15;
        af[mt] = *(const bf16x8*)(Ac + row * 128 + (((kc * 4 + lg) ^ (row & 7)) * 16));
      }
#pragma unroll
      for (int nt = 0; nt < 4; ++nt) {
        const int row = wn * 64 + nt * 16 + l15;
        bfr[nt] = *(const bf16x8*)(Bc + row * 128 + (((kc * 4 + lg) ^ (row & 7)) * 16));
      }
#pragma unroll
      for (int mt = 0; mt < 4; ++mt)
#pragma unroll
        for (int nt = 0; nt < 4; ++nt)
          acc[mt][nt] = __builtin_amdgcn_mfma_f32_16x16x32_bf16(
              af[mt], bfr[nt], acc[mt][nt], 0, 0, 0);
    }
    cur ^= 1;
  }

  if (MODE == 0 && n0 >= 768) {
    // ---- V blocks: transpose via LDS ([128 n][BM t], reuse SH), write VT ----
    const int b = m0 / SEQ, t0 = m0 - b * SEQ;
    __syncthreads();
#pragma unroll
    for (int mt = 0; mt < 4; ++mt)
#pragma unroll
      for (int nt = 0; nt < 4; ++nt)
#pragma unroll
        for (int r = 0; r < 4; ++r) {
          const int tl = wm * 64 + mt * 16 + lg * 4 + r;
          const int nl = wn * 64 + nt * 16 + l15;
          SH[nl * BM + ((tl >> 3) ^ (nl & 7)) * 8 + (tl & 7)] = nbf(acc[mt][nt][r]);
        }
    __syncthreads();
    constexpr int UROW = BM / 8;                    // units per row (24)
#pragma unroll
    for (int j = 0; j < 8; ++j) {                   // 128*UROW/THREADS == 8
      const int u = j * THREADS + tid;
      const int row = u / UROW, un = u - row * UROW;
      int4 vv = *(const int4*)(SH + row * BM + ((un ^ (row & 7)) * 8));
      const int cg = (n0 - 768) + row;
      const int h = cg >> 6, d = cg & 63;
      *(int4*)(VT + ((size_t)(b * NHEAD + h) * HSZ + d) * SEQ + t0 + un * 8) = vv;
    }
    return;
  }

#pragma unroll
  for (int mt = 0; mt < 4; ++mt) {
#pragma unroll
    for (int nt = 0; nt < 4; ++nt) {
#pragma unroll
      for (int r = 0; r < 4; ++r) {
        const int m = m0 + wm * 64 + mt * 16 + lg * 4 + r;
        const int n = n0 + wn * 64 + nt * 16 + l15;
        const float v = acc[mt][nt][r];
        if (MODE == 0) {
          const int which = n / EMBED;   // 0=Q, 1=K here (V handled above)
          const int c = n - which * EMBED;
          const int h = c >> 6, d = c & 63;
          const int b = m / SEQ, t = m - b * SEQ;
          const size_t off = ((size_t)((b * NHEAD + h) * SEQ + t)) * HSZ + d;
          unsigned short* dstp = (which == 0) ? Qb : Kb;
          dstp[off] = nbf(which == 0 ? v * 0.125f : v);  // fold 1/sqrt(D) into Q
        } else {
          Co[(size_t)m * EMBED + n] = v + bias[n];
        }
      }
    }
  }
}

// ---------------- flash attention, causal, TRIPLE q-tiles per block ----------
// grid (8, 96): bh = (by/4)*8+bx (same-bh blocks share an XCD's L2).
// Block trip handles q-tiles {Q0,Q1,Q2}[trip]; one staged K/V tile feeds up
// to 3 R6-verbatim tile() calls. 768 blocks = exactly 3/CU (LDS 40KB).
__global__ __launch_bounds__(256, 3) void attn(const unsigned short* __restrict__ Qb,
                                               const unsigned short* __restrict__ Kb,
                                               const unsigned short* __restrict__ VT,
                                               unsigned short* __restrict__ AO) {
  __shared__ __align__(16) short Kt[2][64 * 64];   // [kv][d] swizzled, dbuf
  __shared__ __align__(16) short Vt[2][64 * 64];   // [d][kv] swizzled, dbuf
  __shared__ __align__(16) short Pl[4][16 * 64];   // per-wave P[q][kv] swizzled
  const int tid = threadIdx.x, lane = tid & 63, w = tid >> 6;
  const int l15 = lane & 15, lg = lane >> 4;
  const int trip = blockIdx.y & 3;
  const int bh = (blockIdx.y >> 2) * 8 + blockIdx.x;
  // balanced triples of q-tiles (each Σ(qt+1) = 19 or 20):
  const int q0t = trip;                                            // 0 1 2 3
  const int q1t = (trip == 3) ? 4 : trip + 5;                      // 5 6 7 4
  const int q2t = (trip == 0) ? 11 : (trip == 1) ? 10 : (trip == 2) ? 8 : 9;
  const size_t base = (size_t)bh * SEQ * HSZ;      // Qb/Kb [bh][t][d]
  char* pw = (char*)(&Pl[w][0]);

  bf16x8 qf0[2], qf1[2], qf2[2];
#pragma unroll
  for (int kc = 0; kc < 2; ++kc) {
    qf0[kc] = *(const bf16x8*)(Qb + base + (size_t)(q0t * 64 + w * 16 + l15) * HSZ +
                               kc * 32 + lg * 8);
    qf1[kc] = *(const bf16x8*)(Qb + base + (size_t)(q1t * 64 + w * 16 + l15) * HSZ +
                               kc * 32 + lg * 8);
    qf2[kc] = *(const bf16x8*)(Qb + base + (size_t)(q2t * 64 + w * 16 + l15) * HSZ +
                               kc * 32 + lg * 8);
  }

  f32x4 o0[4], o1[4], o2[4];
  float m0s = -3.0e38f, l0s = 0.f, m1s = -3.0e38f, l1s = 0.f;
  float m2s = -3.0e38f, l2s = 0.f;
#pragma unroll
  for (int nt = 0; nt < 4; ++nt) {
    o0[nt] = f32x4{0.f, 0.f, 0.f, 0.f};
    o1[nt] = f32x4{0.f, 0.f, 0.f, 0.f};
    o2[nt] = f32x4{0.f, 0.f, 0.f, 0.f};
  }

  auto stage = [&](int kt, int buf) {
#pragma unroll
    for (int j = 0; j < 2; ++j) {
      const int u = j * 256 + tid;
      const int row = u >> 3, un = u & 7;
      const int sw = (un ^ (row & 7)) * 8;
      const int ub = (j * 256 + (tid & ~63)) * 8;
      GLD16(Kb + base + (size_t)(kt * 64 + row) * HSZ + sw, &Kt[buf][ub]);
      GLD16(VT + base + (size_t)row * SEQ + kt * 64 + sw, &Vt[buf][ub]);
    }
  };

  // R6-verbatim tile: S^T = mfma(K,Q); lane owns q=l15; O^T += mfma(V^T,P)
  auto tile = [&](const bf16x8* qf, const bf16x8 kf[2][4], const char* Vc,
                  f32x4* o, float& m, float& l, bool diag) {
    f32x4 s[4];
#pragma unroll
    for (int nt = 0; nt < 4; ++nt) s[nt] = f32x4{0.f, 0.f, 0.f, 0.f};
    __builtin_amdgcn_s_setprio(1);
#pragma unroll
    for (int kc = 0; kc < 2; ++kc)
#pragma unroll
      for (int nt = 0; nt < 4; ++nt)
        s[nt] = __builtin_amdgcn_mfma_f32_16x16x32_bf16(kf[kc][nt], qf[kc], s[nt],
                                                        0, 0, 0);
    __builtin_amdgcn_s_setprio(0);
    if (diag) {
#pragma unroll
      for (int nt = 0; nt < 4; ++nt)
#pragma unroll
        for (int r = 0; r < 4; ++r)
          if (nt * 16 + lg * 4 + r > w * 16 + l15) s[nt][r] = -3.0e38f;
    }
    float mx = s[0][0];
#pragma unroll
    for (int nt = 0; nt < 4; ++nt)
#pragma unroll
      for (int r = 0; r < 4; ++r) mx = fmaxf(mx, s[nt][r]);
    mx = fmaxf(mx, __shfl_xor(mx, 16, 64));
    mx = fmaxf(mx, __shfl_xor(mx, 32, 64));
    const float mn = fmaxf(m, mx);
    const float alpha = __expf(m - mn);
    m = mn;
    float srow = 0.f;
#pragma unroll
    for (int nt = 0; nt < 4; ++nt)
#pragma unroll
      for (int r = 0; r < 4; ++r) {
        const float e = __expf(s[nt][r] - mn);
        s[nt][r] = e;
        srow += e;
      }
    srow += __shfl_xor(srow, 16, 64);
    srow += __shfl_xor(srow, 32, 64);
    l = l * alpha + srow;
#pragma unroll
    for (int nt = 0; nt < 4; ++nt) o[nt] *= alpha;
#pragma unroll
    for (int nt = 0; nt < 4; ++nt) {
      const int kv = nt * 16 + lg * 4;
      int2 pv;
      pv.x = (int)pk2(s[nt][0], s[nt][1]);
      pv.y = (int)pk2(s[nt][2], s[nt][3]);
      *(int2*)(pw + l15 * 128 + (((kv >> 3) ^ (l15 & 7)) * 16) + (kv & 7) * 2) = pv;
    }
    asm volatile("" ::: "memory");
    bf16x8 pf[2];
#pragma unroll
    for (int kc = 0; kc < 2; ++kc)
      pf[kc] = *(const bf16x8*)(pw + l15 * 128 + (((kc * 4 + lg) ^ (l15 & 7)) * 16));
    __builtin_amdgcn_s_setprio(1);
#pragma unroll
    for (int kc = 0; kc < 2; ++kc)
#pragma unroll
      for (int nt = 0; nt < 4; ++nt) {
        const int row = nt * 16 + l15;
        bf16x8 vf = *(const bf16x8*)(Vc + row * 128 +
                                     (((kc * 4 + lg) ^ (row & 7)) * 16));
        o[nt] = __builtin_amdgcn_mfma_f32_16x16x32_bf16(vf, pf[kc], o[nt], 0, 0, 0);
      }
    __builtin_amdgcn_s_setprio(0);
  };

  stage(0, 0);
  int cur = 0;
#pragma unroll 1
  for (int kt = 0; kt <= q2t; ++kt) {
    __syncthreads();                        // buf[cur] staged; buf[cur^1] free
    if (kt < q2t) stage(kt + 1, cur ^ 1);   // loads fly under compute
    const char* Kc = (const char*)Kt[cur];
    const char* Vc = (const char*)Vt[cur];
    bf16x8 kf[2][4];
#pragma unroll
    for (int kc = 0; kc < 2; ++kc)
#pragma unroll
      for (int nt = 0; nt < 4; ++nt) {
        const int row = nt * 16 + l15;
        kf[kc][nt] = *(const bf16x8*)(Kc + row * 128 +
                                      (((kc * 4 + lg) ^ (row & 7)) * 16));
      }
    tile(qf2, kf, Vc, o2, m2s, l2s, kt == q2t);
    if (kt <= q1t) tile(qf1, kf, Vc, o1, m1s, l1s, kt == q1t);
    if (kt <= q0t) tile(qf0, kf, Vc, o0, m0s, l0s, kt == q0t);
    cur ^= 1;
  }

  // epilogue: lane holds O[q=l15][d=nt*16+lg*4+r]; ushort4 stores x3
  const int bq = bh / NHEAD, h = bh - bq * NHEAD;
  const float inv0 = 1.f / l0s, inv1 = 1.f / l1s, inv2 = 1.f / l2s;
#pragma unroll
  for (int nt = 0; nt < 4; ++nt) {
    ushort4 s0, s1, s2;
    s0.x = nbf(o0[nt][0] * inv0); s0.y = nbf(o0[nt][1] * inv0);
    s0.z = nbf(o0[nt][2] * inv0); s0.w = nbf(o0[nt][3] * inv0);
    s1.x = nbf(o1[nt][0] * inv1); s1.y = nbf(o1[nt][1] * inv1);
    s1.z = nbf(o1[nt][2] * inv1); s1.w = nbf(o1[nt][3] * inv1);
    s2.x = nbf(o2[nt][0] * inv2); s2.y = nbf(o2[nt][1] * inv2);
    s2.z = nbf(o2[nt][2] * inv2); s2.w = nbf(o2[nt][3] * inv2);
    const int col = h * HSZ + nt * 16 + lg * 4;
    *(ushort4*)(AO + ((size_t)(bq * SEQ + q0t * 64 + w * 16 + l15)) * EMBED + col) = s0;
    *(ushort4*)(AO + ((size_t)(bq * SEQ + q1t * 64 + w * 16 + l15)) * EMBED + col) = s1;
    *(ushort4*)(AO + ((size_t)(bq * SEQ + q2t * 64 + w * 16 + l15)) * EMBED + col) = s2;
  }
}

extern "C" void kernel_launch(void* const* d_in, const int* in_sizes, int n_in,
                              void* d_out, int out_size, void* d_ws, size_t ws_size,
                              hipStream_t stream) {
  const float* X  = (const float*)d_in[0];
  const float* Wq = (const float*)d_in[1];
  const float* Wk = (const float*)d_in[2];
  const float* Wv = (const float*)d_in[3];
  const float* Wo = (const float*)d_in[4];
  const float* bo = (const float*)d_in[5];
  float* out = (float*)d_out;

  const size_t NW = (size_t)EMBED * EMBED;   // 147456
  const size_t NX = (size_t)MROWS * EMBED;   // 9437184
  unsigned short* ws    = (unsigned short*)d_ws;
  unsigned short* Wqkvb = ws;                // 3*NW
  unsigned short* Wob   = Wqkvb + 3 * NW;    // NW (contiguous after Wqkvb)
  unsigned short* XbAO  = Wob + NW;          // NX: Xb (pre-attn) then AO
  unsigned short* Qb    = XbAO + NX;         // NX  [B,H,T,D]
  unsigned short* Kb    = Qb + NX;           // NX  [B,H,T,D]
  unsigned short* VTb   = Kb + NX;           // NX  [B,H,D,T] (transposed V)
  // total: 4*NW + 4*NX ushorts = 76.7 MB of d_ws

  cvtAll<<<(int)((NX + 4 * NW) / 4 / 256), 256, 0, stream>>>(
      X, Wq, Wk, Wv, Wo, Wqkvb, XbAO);

  gemm_bt<0><<<dim3(MROWS / 192, (3 * EMBED) / 128), 384, 0, stream>>>(
      XbAO, Wqkvb, Qb, Kb, VTb, nullptr, nullptr);

  attn<<<dim3(8, 96), 256, 0, stream>>>(Qb, Kb, VTb, XbAO);

  gemm_bt<1><<<dim3(MROWS / 128, EMBED / 128), 256, 0, stream>>>(
      XbAO, Wob, nullptr, nullptr, nullptr, out, bo);
}

// Round 10
// 104.809 us; speedup vs baseline: 1.1771x; 1.0497x over previous
//
#include <hip/hip_runtime.h>
#include <stdint.h>

#define EMBED 384
#define NHEAD 6
#define HSZ   64
#define BATCH 32
#define SEQ   768
#define MROWS (BATCH * SEQ)   // 24576
#define NTILE (SEQ / 64)      // 12

typedef __bf16 bf16x8 __attribute__((ext_vector_type(8)));
typedef float  f32x4  __attribute__((ext_vector_type(4)));

#define GLD16(gp, lp)                                                        \
  __builtin_amdgcn_global_load_lds(                                          \
      (const __attribute__((address_space(1))) void*)(gp),                   \
      (__attribute__((address_space(3))) void*)(lp), 16, 0, 0)

__device__ inline unsigned short nbf(float f) {   // native RNE convert
  union { __bf16 b; unsigned short s; } c; c.b = (__bf16)f; return c.s;
}
__device__ inline uint32_t pk2(float a, float b) { // -> v_cvt_pk_bf16_f32
  union { __bf16 b[2]; uint32_t u; } c;
  c.b[0] = (__bf16)a; c.b[1] = (__bf16)b; return c.u;
}

// ---------------- fused fp32 -> bf16 convert: X then Wq|Wk|Wv|Wo ------------
__global__ __launch_bounds__(256) void cvtAll(const float* __restrict__ X,
                                              const float* __restrict__ Wq,
                                              const float* __restrict__ Wk,
                                              const float* __restrict__ Wv,
                                              const float* __restrict__ Wo,
                                              unsigned short* __restrict__ dstW,
                                              unsigned short* __restrict__ dstX) {
  const int NX = MROWS * EMBED, NW = EMBED * EMBED;
  int i = (blockIdx.x * 256 + threadIdx.x) * 4;
  const float* src;
  unsigned short* dst;
  if (i < NX) {
    src = X + i; dst = dstX + i;
  } else {
    int j = i - NX;
    int wsel = j / NW, r = j - wsel * NW;
    src = ((wsel == 0) ? Wq : (wsel == 1) ? Wk : (wsel == 2) ? Wv : Wo) + r;
    dst = dstW + j;
  }
  float4 v = *reinterpret_cast<const float4*>(src);
  uint2 o;
  o.x = pk2(v.x, v.y); o.y = pk2(v.z, v.w);
  *reinterpret_cast<uint2*>(dst) = o;
}

// ---------------- GEMM: C[m,n] = sum_k A[m,k] * B[n,k]  (B stored [N][K]) ----
// R6-proven: BM=128, 4 waves, 2-phase double-buffered global_load_lds staging.
// MODE 0: scatters Q/K bf16 (Q scaled 0.125); V written transposed VT[bh][d][t].
// MODE 1: fp32 out + bias.
template <int MODE>
__global__ __launch_bounds__(256) void gemm_bt(
    const unsigned short* __restrict__ Ab,
    const unsigned short* __restrict__ Bw,
    unsigned short* __restrict__ Qb,
    unsigned short* __restrict__ Kb,
    unsigned short* __restrict__ VT,
    float* __restrict__ Co,
    const float* __restrict__ bias) {
  __shared__ __align__(16) short SH[32768];   // 64KB: 2 bufs x (A 16KB + B 16KB)
  const int tid = threadIdx.x;
  const int lane = tid & 63;
  const int w = tid >> 6;
  const int wm = w >> 1, wn = w & 1;
  const int m0 = blockIdx.x * 128, n0 = blockIdx.y * 128;
  const int l15 = lane & 15, lg = lane >> 4;
  char* shc = (char*)SH;

  auto stage = [&](int kt, int buf) {
    short* At = SH + buf * 16384;
    short* Bt = At + 8192;
    const int k0 = kt * 64;
#pragma unroll
    for (int j = 0; j < 4; ++j) {
      const int u = j * 256 + tid;
      const int row = u >> 3, un = u & 7;
      const int sw = (un ^ (row & 7)) * 8;
      const int ub = (j * 256 + (tid & ~63)) * 8;
      GLD16(Ab + (size_t)(m0 + row) * EMBED + k0 + sw, At + ub);
      GLD16(Bw + (size_t)(n0 + row) * EMBED + k0 + sw, Bt + ub);
    }
  };

  f32x4 acc[4][4];
#pragma unroll
  for (int i = 0; i < 4; ++i)
#pragma unroll
    for (int j = 0; j < 4; ++j) acc[i][j] = f32x4{0.f, 0.f, 0.f, 0.f};

  stage(0, 0);
  int cur = 0;
#pragma unroll 1
  for (int kt = 0; kt < 6; ++kt) {
    __syncthreads();                        // drains stage(kt) [vmcnt(0) auto]
    if (kt < 5) stage(kt + 1, cur ^ 1);     // next-tile loads fly under MFMA
    const char* Ac = shc + cur * 32768;
    const char* Bc = Ac + 16384;
#pragma unroll
    for (int kc = 0; kc < 2; ++kc) {
      bf16x8 af[4], bfr[4];
#pragma unroll
      for (int mt = 0; mt < 4; ++mt) {
        const int row = wm * 64 + mt * 16 + l15;
        af[mt] = *(const bf16x8*)(Ac + row * 128 + (((kc * 4 + lg) ^ (row & 7)) * 16));
      }
#pragma unroll
      for (int nt = 0; nt < 4; ++nt) {
        const int row = wn * 64 + nt * 16 + l15;
        bfr[nt] = *(const bf16x8*)(Bc + row * 128 + (((kc * 4 + lg) ^ (row & 7)) * 16));
      }
#pragma unroll
      for (int mt = 0; mt < 4; ++mt)
#pragma unroll
        for (int nt = 0; nt < 4; ++nt)
          acc[mt][nt] = __builtin_amdgcn_mfma_f32_16x16x32_bf16(
              af[mt], bfr[nt], acc[mt][nt], 0, 0, 0);
    }
    cur ^= 1;
  }

  if (MODE == 0 && n0 >= 768) {
    // ---- V blocks: transpose via LDS (reuse buf0, 32KB), write VT coalesced --
    const int b = m0 / SEQ, t0 = m0 - b * SEQ;
    __syncthreads();
#pragma unroll
    for (int mt = 0; mt < 4; ++mt)
#pragma unroll
      for (int nt = 0; nt < 4; ++nt)
#pragma unroll
        for (int r = 0; r < 4; ++r) {
          const int tl = wm * 64 + mt * 16 + lg * 4 + r;
          const int nl = wn * 64 + nt * 16 + l15;
          *(unsigned short*)(shc + nl * 256 + (((tl >> 3) ^ (nl & 7)) * 16) +
                             (tl & 7) * 2) = nbf(acc[mt][nt][r]);
        }
    __syncthreads();
#pragma unroll
    for (int j = 0; j < 8; ++j) {
      const int u = j * 256 + tid;
      const int row = u >> 4, un = u & 15;
      int4 vv = *(const int4*)(shc + row * 256 + ((un ^ (row & 7)) * 16));
      const int cg = (n0 - 768) + row;
      const int h = cg >> 6, d = cg & 63;
      *(int4*)(VT + ((size_t)(b * NHEAD + h) * HSZ + d) * SEQ + t0 + un * 8) = vv;
    }
    return;
  }

#pragma unroll
  for (int mt = 0; mt < 4; ++mt) {
#pragma unroll
    for (int nt = 0; nt < 4; ++nt) {
#pragma unroll
      for (int r = 0; r < 4; ++r) {
        const int m = m0 + wm * 64 + mt * 16 + lg * 4 + r;
        const int n = n0 + wn * 64 + nt * 16 + l15;
        const float v = acc[mt][nt][r];
        if (MODE == 0) {
          const int which = n / EMBED;   // 0=Q, 1=K here (V handled above)
          const int c = n - which * EMBED;
          const int h = c >> 6, d = c & 63;
          const int b = m / SEQ, t = m - b * SEQ;
          const size_t off = ((size_t)((b * NHEAD + h) * SEQ + t)) * HSZ + d;
          unsigned short* dstp = (which == 0) ? Qb : Kb;
          dstp[off] = nbf(which == 0 ? v * 0.125f : v);  // fold 1/sqrt(D) into Q
        } else {
          Co[(size_t)m * EMBED + n] = v + bias[n];
        }
      }
    }
  }
}

// ---------------- flash attention, causal, TRIPLE q-tiles per block ----------
// grid (8, 96): bh = (by/4)*8+bx (same-bh blocks share an XCD's L2).
// Block trip handles q-tiles {Q0,Q1,Q2}[trip]; one staged K/V tile feeds up
// to 3 R6-verbatim tile() calls. 768 blocks = exactly 3/CU (LDS 40KB).
__global__ __launch_bounds__(256, 3) void attn(const unsigned short* __restrict__ Qb,
                                               const unsigned short* __restrict__ Kb,
                                               const unsigned short* __restrict__ VT,
                                               unsigned short* __restrict__ AO) {
  __shared__ __align__(16) short Kt[2][64 * 64];   // [kv][d] swizzled, dbuf
  __shared__ __align__(16) short Vt[2][64 * 64];   // [d][kv] swizzled, dbuf
  __shared__ __align__(16) short Pl[4][16 * 64];   // per-wave P[q][kv] swizzled
  const int tid = threadIdx.x, lane = tid & 63, w = tid >> 6;
  const int l15 = lane & 15, lg = lane >> 4;
  const int trip = blockIdx.y & 3;
  const int bh = (blockIdx.y >> 2) * 8 + blockIdx.x;
  // balanced triples of q-tiles (each Σ(qt+1) = 19 or 20):
  const int q0t = trip;                                            // 0 1 2 3
  const int q1t = (trip == 3) ? 4 : trip + 5;                      // 5 6 7 4
  const int q2t = (trip == 0) ? 11 : (trip == 1) ? 10 : (trip == 2) ? 8 : 9;
  const size_t base = (size_t)bh * SEQ * HSZ;      // Qb/Kb [bh][t][d]
  char* pw = (char*)(&Pl[w][0]);

  bf16x8 qf0[2], qf1[2], qf2[2];
#pragma unroll
  for (int kc = 0; kc < 2; ++kc) {
    qf0[kc] = *(const bf16x8*)(Qb + base + (size_t)(q0t * 64 + w * 16 + l15) * HSZ +
                               kc * 32 + lg * 8);
    qf1[kc] = *(const bf16x8*)(Qb + base + (size_t)(q1t * 64 + w * 16 + l15) * HSZ +
                               kc * 32 + lg * 8);
    qf2[kc] = *(const bf16x8*)(Qb + base + (size_t)(q2t * 64 + w * 16 + l15) * HSZ +
                               kc * 32 + lg * 8);
  }

  f32x4 o0[4], o1[4], o2[4];
  float m0s = -3.0e38f, l0s = 0.f, m1s = -3.0e38f, l1s = 0.f;
  float m2s = -3.0e38f, l2s = 0.f;
#pragma unroll
  for (int nt = 0; nt < 4; ++nt) {
    o0[nt] = f32x4{0.f, 0.f, 0.f, 0.f};
    o1[nt] = f32x4{0.f, 0.f, 0.f, 0.f};
    o2[nt] = f32x4{0.f, 0.f, 0.f, 0.f};
  }

  auto stage = [&](int kt, int buf) {
#pragma unroll
    for (int j = 0; j < 2; ++j) {
      const int u = j * 256 + tid;
      const int row = u >> 3, un = u & 7;
      const int sw = (un ^ (row & 7)) * 8;
      const int ub = (j * 256 + (tid & ~63)) * 8;
      GLD16(Kb + base + (size_t)(kt * 64 + row) * HSZ + sw, &Kt[buf][ub]);
      GLD16(VT + base + (size_t)row * SEQ + kt * 64 + sw, &Vt[buf][ub]);
    }
  };

  // R6-verbatim tile: S^T = mfma(K,Q); lane owns q=l15; O^T += mfma(V^T,P)
  auto tile = [&](const bf16x8* qf, const bf16x8 kf[2][4], const char* Vc,
                  f32x4* o, float& m, float& l, bool diag) {
    f32x4 s[4];
#pragma unroll
    for (int nt = 0; nt < 4; ++nt) s[nt] = f32x4{0.f, 0.f, 0.f, 0.f};
    __builtin_amdgcn_s_setprio(1);
#pragma unroll
    for (int kc = 0; kc < 2; ++kc)
#pragma unroll
      for (int nt = 0; nt < 4; ++nt)
        s[nt] = __builtin_amdgcn_mfma_f32_16x16x32_bf16(kf[kc][nt], qf[kc], s[nt],
                                                        0, 0, 0);
    __builtin_amdgcn_s_setprio(0);
    if (diag) {
#pragma unroll
      for (int nt = 0; nt < 4; ++nt)
#pragma unroll
        for (int r = 0; r < 4; ++r)
          if (nt * 16 + lg * 4 + r > w * 16 + l15) s[nt][r] = -3.0e38f;
    }
    float mx = s[0][0];
#pragma unroll
    for (int nt = 0; nt < 4; ++nt)
#pragma unroll
      for (int r = 0; r < 4; ++r) mx = fmaxf(mx, s[nt][r]);
    mx = fmaxf(mx, __shfl_xor(mx, 16, 64));
    mx = fmaxf(mx, __shfl_xor(mx, 32, 64));
    const float mn = fmaxf(m, mx);
    const float alpha = __expf(m - mn);
    m = mn;
    float srow = 0.f;
#pragma unroll
    for (int nt = 0; nt < 4; ++nt)
#pragma unroll
      for (int r = 0; r < 4; ++r) {
        const float e = __expf(s[nt][r] - mn);
        s[nt][r] = e;
        srow += e;
      }
    srow += __shfl_xor(srow, 16, 64);
    srow += __shfl_xor(srow, 32, 64);
    l = l * alpha + srow;
#pragma unroll
    for (int nt = 0; nt < 4; ++nt) o[nt] *= alpha;
#pragma unroll
    for (int nt = 0; nt < 4; ++nt) {
      const int kv = nt * 16 + lg * 4;
      int2 pv;
      pv.x = (int)pk2(s[nt][0], s[nt][1]);
      pv.y = (int)pk2(s[nt][2], s[nt][3]);
      *(int2*)(pw + l15 * 128 + (((kv >> 3) ^ (l15 & 7)) * 16) + (kv & 7) * 2) = pv;
    }
    asm volatile("" ::: "memory");
    bf16x8 pf[2];
#pragma unroll
    for (int kc = 0; kc < 2; ++kc)
      pf[kc] = *(const bf16x8*)(pw + l15 * 128 + (((kc * 4 + lg) ^ (l15 & 7)) * 16));
    __builtin_amdgcn_s_setprio(1);
#pragma unroll
    for (int kc = 0; kc < 2; ++kc)
#pragma unroll
      for (int nt = 0; nt < 4; ++nt) {
        const int row = nt * 16 + l15;
        bf16x8 vf = *(const bf16x8*)(Vc + row * 128 +
                                     (((kc * 4 + lg) ^ (row & 7)) * 16));
        o[nt] = __builtin_amdgcn_mfma_f32_16x16x32_bf16(vf, pf[kc], o[nt], 0, 0, 0);
      }
    __builtin_amdgcn_s_setprio(0);
  };

  stage(0, 0);
  int cur = 0;
#pragma unroll 1
  for (int kt = 0; kt <= q2t; ++kt) {
    __syncthreads();                        // buf[cur] staged; buf[cur^1] free
    if (kt < q2t) stage(kt + 1, cur ^ 1);   // loads fly under compute
    const char* Kc = (const char*)Kt[cur];
    const char* Vc = (const char*)Vt[cur];
    bf16x8 kf[2][4];
#pragma unroll
    for (int kc = 0; kc < 2; ++kc)
#pragma unroll
      for (int nt = 0; nt < 4; ++nt) {
        const int row = nt * 16 + l15;
        kf[kc][nt] = *(const bf16x8*)(Kc + row * 128 +
                                      (((kc * 4 + lg) ^ (row & 7)) * 16));
      }
    tile(qf2, kf, Vc, o2, m2s, l2s, kt == q2t);
    if (kt <= q1t) tile(qf1, kf, Vc, o1, m1s, l1s, kt == q1t);
    if (kt <= q0t) tile(qf0, kf, Vc, o0, m0s, l0s, kt == q0t);
    cur ^= 1;
  }

  // epilogue: lane holds O[q=l15][d=nt*16+lg*4+r]; ushort4 stores x3
  const int bq = bh / NHEAD, h = bh - bq * NHEAD;
  const float inv0 = 1.f / l0s, inv1 = 1.f / l1s, inv2 = 1.f / l2s;
#pragma unroll
  for (int nt = 0; nt < 4; ++nt) {
    ushort4 s0, s1, s2;
    s0.x = nbf(o0[nt][0] * inv0); s0.y = nbf(o0[nt][1] * inv0);
    s0.z = nbf(o0[nt][2] * inv0); s0.w = nbf(o0[nt][3] * inv0);
    s1.x = nbf(o1[nt][0] * inv1); s1.y = nbf(o1[nt][1] * inv1);
    s1.z = nbf(o1[nt][2] * inv1); s1.w = nbf(o1[nt][3] * inv1);
    s2.x = nbf(o2[nt][0] * inv2); s2.y = nbf(o2[nt][1] * inv2);
    s2.z = nbf(o2[nt][2] * inv2); s2.w = nbf(o2[nt][3] * inv2);
    const int col = h * HSZ + nt * 16 + lg * 4;
    *(ushort4*)(AO + ((size_t)(bq * SEQ + q0t * 64 + w * 16 + l15)) * EMBED + col) = s0;
    *(ushort4*)(AO + ((size_t)(bq * SEQ + q1t * 64 + w * 16 + l15)) * EMBED + col) = s1;
    *(ushort4*)(AO + ((size_t)(bq * SEQ + q2t * 64 + w * 16 + l15)) * EMBED + col) = s2;
  }
}

extern "C" void kernel_launch(void* const* d_in, const int* in_sizes, int n_in,
                              void* d_out, int out_size, void* d_ws, size_t ws_size,
                              hipStream_t stream) {
  const float* X  = (const float*)d_in[0];
  const float* Wq = (const float*)d_in[1];
  const float* Wk = (const float*)d_in[2];
  const float* Wv = (const float*)d_in[3];
  const float* Wo = (const float*)d_in[4];
  const float* bo = (const float*)d_in[5];
  float* out = (float*)d_out;

  const size_t NW = (size_t)EMBED * EMBED;   // 147456
  const size_t NX = (size_t)MROWS * EMBED;   // 9437184
  unsigned short* ws    = (unsigned short*)d_ws;
  unsigned short* Wqkvb = ws;                // 3*NW
  unsigned short* Wob   = Wqkvb + 3 * NW;    // NW (contiguous after Wqkvb)
  unsigned short* XbAO  = Wob + NW;          // NX: Xb (pre-attn) then AO
  unsigned short* Qb    = XbAO + NX;         // NX  [B,H,T,D]
  unsigned short* Kb    = Qb + NX;           // NX  [B,H,T,D]
  unsigned short* VTb   = Kb + NX;           // NX  [B,H,D,T] (transposed V)
  // total: 4*NW + 4*NX ushorts = 76.7 MB of d_ws

  cvtAll<<<(int)((NX + 4 * NW) / 4 / 256), 256, 0, stream>>>(
      X, Wq, Wk, Wv, Wo, Wqkvb, XbAO);

  gemm_bt<0><<<dim3(MROWS / 128, (3 * EMBED) / 128), 256, 0, stream>>>(
      XbAO, Wqkvb, Qb, Kb, VTb, nullptr, nullptr);

  attn<<<dim3(8, 96), 256, 0, stream>>>(Qb, Kb, VTb, XbAO);

  gemm_bt<1><<<dim3(MROWS / 128, EMBED / 128), 256, 0, stream>>>(
      XbAO, Wob, nullptr, nullptr, nullptr, out, bo);
}

// Round 11
// 103.852 us; speedup vs baseline: 1.1880x; 1.0092x over previous
//
#include <hip/hip_runtime.h>
#include <stdint.h>

#define EMBED 384
#define NHEAD 6
#define HSZ   64
#define BATCH 32
#define SEQ   768
#define MROWS (BATCH * SEQ)   // 24576
#define NTILE (SEQ / 64)      // 12

typedef __bf16 bf16x8 __attribute__((ext_vector_type(8)));
typedef float  f32x4  __attribute__((ext_vector_type(4)));

#define GLD16(gp, lp)                                                        \
  __builtin_amdgcn_global_load_lds(                                          \
      (const __attribute__((address_space(1))) void*)(gp),                   \
      (__attribute__((address_space(3))) void*)(lp), 16, 0, 0)

__device__ inline unsigned short nbf(float f) {   // native RNE convert
  union { __bf16 b; unsigned short s; } c; c.b = (__bf16)f; return c.s;
}
__device__ inline uint32_t pk2(float a, float b) { // -> v_cvt_pk_bf16_f32
  union { __bf16 b[2]; uint32_t u; } c;
  c.b[0] = (__bf16)a; c.b[1] = (__bf16)b; return c.u;
}

// ---------------- fused fp32 -> bf16 convert: X then Wq|Wk|Wv|Wo ------------
__global__ __launch_bounds__(256) void cvtAll(const float* __restrict__ X,
                                              const float* __restrict__ Wq,
                                              const float* __restrict__ Wk,
                                              const float* __restrict__ Wv,
                                              const float* __restrict__ Wo,
                                              unsigned short* __restrict__ dstW,
                                              unsigned short* __restrict__ dstX) {
  const int NX = MROWS * EMBED, NW = EMBED * EMBED;
  int i = (blockIdx.x * 256 + threadIdx.x) * 4;
  const float* src;
  unsigned short* dst;
  if (i < NX) {
    src = X + i; dst = dstX + i;
  } else {
    int j = i - NX;
    int wsel = j / NW, r = j - wsel * NW;
    src = ((wsel == 0) ? Wq : (wsel == 1) ? Wk : (wsel == 2) ? Wv : Wo) + r;
    dst = dstW + j;
  }
  float4 v = *reinterpret_cast<const float4*>(src);
  uint2 o;
  o.x = pk2(v.x, v.y); o.y = pk2(v.z, v.w);
  *reinterpret_cast<uint2*>(dst) = o;
}

// ---------------- GEMM: C[m,n] = sum_k A[m,k] * B[n,k]  (B stored [N][K]) ----
// R6-proven body. 1D grid, XCD-chunked bijective swizzle + n-fastest decompose:
// the NB blocks sharing an A-panel are consecutive work items on ONE XCD -> A
// hits that XCD's L2 instead of being re-fetched from HBM by every n-block.
// MODE 0: NB=9; scatters Q/K bf16 (Q scaled 0.125); V transposed VT[bh][d][t].
// MODE 1: NB=3; fp32 out + bias.
template <int MODE>
__global__ __launch_bounds__(256) void gemm_bt(
    const unsigned short* __restrict__ Ab,
    const unsigned short* __restrict__ Bw,
    unsigned short* __restrict__ Qb,
    unsigned short* __restrict__ Kb,
    unsigned short* __restrict__ VT,
    float* __restrict__ Co,
    const float* __restrict__ bias) {
  constexpr int NB = (MODE == 0) ? 9 : 3;          // n-blocks per m-panel
  constexpr int NWG = (MROWS / 128) * NB;          // 1728 / 576, both %8==0
  __shared__ __align__(16) short SH[32768];   // 64KB: 2 bufs x (A 16KB + B 16KB)
  const int tid = threadIdx.x;
  const int lane = tid & 63;
  const int w = tid >> 6;
  const int wm = w >> 1, wn = w & 1;
  // XCD-chunked bijective swizzle (m204): XCD x gets work [x*NWG/8, (x+1)*NWG/8)
  const int work = ((int)blockIdx.x % 8) * (NWG / 8) + (int)blockIdx.x / 8;
  const int m0 = (work / NB) * 128, n0 = (work % NB) * 128;
  const int l15 = lane & 15, lg = lane >> 4;
  char* shc = (char*)SH;

  auto stage = [&](int kt, int buf) {
    short* At = SH + buf * 16384;
    short* Bt = At + 8192;
    const int k0 = kt * 64;
#pragma unroll
    for (int j = 0; j < 4; ++j) {
      const int u = j * 256 + tid;
      const int row = u >> 3, un = u & 7;
      const int sw = (un ^ (row & 7)) * 8;
      const int ub = (j * 256 + (tid & ~63)) * 8;
      GLD16(Ab + (size_t)(m0 + row) * EMBED + k0 + sw, At + ub);
      GLD16(Bw + (size_t)(n0 + row) * EMBED + k0 + sw, Bt + ub);
    }
  };

  f32x4 acc[4][4];
#pragma unroll
  for (int i = 0; i < 4; ++i)
#pragma unroll
    for (int j = 0; j < 4; ++j) acc[i][j] = f32x4{0.f, 0.f, 0.f, 0.f};

  stage(0, 0);
  int cur = 0;
#pragma unroll 1
  for (int kt = 0; kt < 6; ++kt) {
    __syncthreads();                        // drains stage(kt) [vmcnt(0) auto]
    if (kt < 5) stage(kt + 1, cur ^ 1);     // next-tile loads fly under MFMA
    const char* Ac = shc + cur * 32768;
    const char* Bc = Ac + 16384;
#pragma unroll
    for (int kc = 0; kc < 2; ++kc) {
      bf16x8 af[4], bfr[4];
#pragma unroll
      for (int mt = 0; mt < 4; ++mt) {
        const int row = wm * 64 + mt * 16 + l15;
        af[mt] = *(const bf16x8*)(Ac + row * 128 + (((kc * 4 + lg) ^ (row & 7)) * 16));
      }
#pragma unroll
      for (int nt = 0; nt < 4; ++nt) {
        const int row = wn * 64 + nt * 16 + l15;
        bfr[nt] = *(const bf16x8*)(Bc + row * 128 + (((kc * 4 + lg) ^ (row & 7)) * 16));
      }
#pragma unroll
      for (int mt = 0; mt < 4; ++mt)
#pragma unroll
        for (int nt = 0; nt < 4; ++nt)
          acc[mt][nt] = __builtin_amdgcn_mfma_f32_16x16x32_bf16(
              af[mt], bfr[nt], acc[mt][nt], 0, 0, 0);
    }
    cur ^= 1;
  }

  if (MODE == 0 && n0 >= 768) {
    // ---- V blocks: transpose via LDS (reuse buf0, 32KB), write VT coalesced --
    const int b = m0 / SEQ, t0 = m0 - b * SEQ;
    __syncthreads();
#pragma unroll
    for (int mt = 0; mt < 4; ++mt)
#pragma unroll
      for (int nt = 0; nt < 4; ++nt)
#pragma unroll
        for (int r = 0; r < 4; ++r) {
          const int tl = wm * 64 + mt * 16 + lg * 4 + r;
          const int nl = wn * 64 + nt * 16 + l15;
          *(unsigned short*)(shc + nl * 256 + (((tl >> 3) ^ (nl & 7)) * 16) +
                             (tl & 7) * 2) = nbf(acc[mt][nt][r]);
        }
    __syncthreads();
#pragma unroll
    for (int j = 0; j < 8; ++j) {
      const int u = j * 256 + tid;
      const int row = u >> 4, un = u & 15;
      int4 vv = *(const int4*)(shc + row * 256 + ((un ^ (row & 7)) * 16));
      const int cg = (n0 - 768) + row;
      const int h = cg >> 6, d = cg & 63;
      *(int4*)(VT + ((size_t)(b * NHEAD + h) * HSZ + d) * SEQ + t0 + un * 8) = vv;
    }
    return;
  }

#pragma unroll
  for (int mt = 0; mt < 4; ++mt) {
#pragma unroll
    for (int nt = 0; nt < 4; ++nt) {
#pragma unroll
      for (int r = 0; r < 4; ++r) {
        const int m = m0 + wm * 64 + mt * 16 + lg * 4 + r;
        const int n = n0 + wn * 64 + nt * 16 + l15;
        const float v = acc[mt][nt][r];
        if (MODE == 0) {
          const int which = n / EMBED;   // 0=Q, 1=K here (V handled above)
          const int c = n - which * EMBED;
          const int h = c >> 6, d = c & 63;
          const int b = m / SEQ, t = m - b * SEQ;
          const size_t off = ((size_t)((b * NHEAD + h) * SEQ + t)) * HSZ + d;
          unsigned short* dstp = (which == 0) ? Qb : Kb;
          dstp[off] = nbf(which == 0 ? v * 0.125f : v);  // fold 1/sqrt(D) into Q
        } else {
          Co[(size_t)m * EMBED + n] = v + bias[n];
        }
      }
    }
  }
}

// ---------------- flash attention, causal, TRIPLE q-tiles per block ----------
// grid (8, 96): bh = (by/4)*8+bx (same-bh blocks share an XCD's L2).
// Block trip handles q-tiles {Q0,Q1,Q2}[trip]; one staged K/V tile feeds up
// to 3 R6-verbatim tile() calls. 768 blocks = exactly 3/CU (LDS 40KB).
__global__ __launch_bounds__(256, 3) void attn(const unsigned short* __restrict__ Qb,
                                               const unsigned short* __restrict__ Kb,
                                               const unsigned short* __restrict__ VT,
                                               unsigned short* __restrict__ AO) {
  __shared__ __align__(16) short Kt[2][64 * 64];   // [kv][d] swizzled, dbuf
  __shared__ __align__(16) short Vt[2][64 * 64];   // [d][kv] swizzled, dbuf
  __shared__ __align__(16) short Pl[4][16 * 64];   // per-wave P[q][kv] swizzled
  const int tid = threadIdx.x, lane = tid & 63, w = tid >> 6;
  const int l15 = lane & 15, lg = lane >> 4;
  const int trip = blockIdx.y & 3;
  const int bh = (blockIdx.y >> 2) * 8 + blockIdx.x;
  // balanced triples of q-tiles (each Σ(qt+1) = 19 or 20):
  const int q0t = trip;                                            // 0 1 2 3
  const int q1t = (trip == 3) ? 4 : trip + 5;                      // 5 6 7 4
  const int q2t = (trip == 0) ? 11 : (trip == 1) ? 10 : (trip == 2) ? 8 : 9;
  const size_t base = (size_t)bh * SEQ * HSZ;      // Qb/Kb [bh][t][d]
  char* pw = (char*)(&Pl[w][0]);

  bf16x8 qf0[2], qf1[2], qf2[2];
#pragma unroll
  for (int kc = 0; kc < 2; ++kc) {
    qf0[kc] = *(const bf16x8*)(Qb + base + (size_t)(q0t * 64 + w * 16 + l15) * HSZ +
                               kc * 32 + lg * 8);
    qf1[kc] = *(const bf16x8*)(Qb + base + (size_t)(q1t * 64 + w * 16 + l15) * HSZ +
                               kc * 32 + lg * 8);
    qf2[kc] = *(const bf16x8*)(Qb + base + (size_t)(q2t * 64 + w * 16 + l15) * HSZ +
                               kc * 32 + lg * 8);
  }

  f32x4 o0[4], o1[4], o2[4];
  float m0s = -3.0e38f, l0s = 0.f, m1s = -3.0e38f, l1s = 0.f;
  float m2s = -3.0e38f, l2s = 0.f;
#pragma unroll
  for (int nt = 0; nt < 4; ++nt) {
    o0[nt] = f32x4{0.f, 0.f, 0.f, 0.f};
    o1[nt] = f32x4{0.f, 0.f, 0.f, 0.f};
    o2[nt] = f32x4{0.f, 0.f, 0.f, 0.f};
  }

  auto stage = [&](int kt, int buf) {
#pragma unroll
    for (int j = 0; j < 2; ++j) {
      const int u = j * 256 + tid;
      const int row = u >> 3, un = u & 7;
      const int sw = (un ^ (row & 7)) * 8;
      const int ub = (j * 256 + (tid & ~63)) * 8;
      GLD16(Kb + base + (size_t)(kt * 64 + row) * HSZ + sw, &Kt[buf][ub]);
      GLD16(VT + base + (size_t)row * SEQ + kt * 64 + sw, &Vt[buf][ub]);
    }
  };

  // R6-verbatim tile: S^T = mfma(K,Q); lane owns q=l15; O^T += mfma(V^T,P)
  auto tile = [&](const bf16x8* qf, const bf16x8 kf[2][4], const char* Vc,
                  f32x4* o, float& m, float& l, bool diag) {
    f32x4 s[4];
#pragma unroll
    for (int nt = 0; nt < 4; ++nt) s[nt] = f32x4{0.f, 0.f, 0.f, 0.f};
    __builtin_amdgcn_s_setprio(1);
#pragma unroll
    for (int kc = 0; kc < 2; ++kc)
#pragma unroll
      for (int nt = 0; nt < 4; ++nt)
        s[nt] = __builtin_amdgcn_mfma_f32_16x16x32_bf16(kf[kc][nt], qf[kc], s[nt],
                                                        0, 0, 0);
    __builtin_amdgcn_s_setprio(0);
    if (diag) {
#pragma unroll
      for (int nt = 0; nt < 4; ++nt)
#pragma unroll
        for (int r = 0; r < 4; ++r)
          if (nt * 16 + lg * 4 + r > w * 16 + l15) s[nt][r] = -3.0e38f;
    }
    float mx = s[0][0];
#pragma unroll
    for (int nt = 0; nt < 4; ++nt)
#pragma unroll
      for (int r = 0; r < 4; ++r) mx = fmaxf(mx, s[nt][r]);
    mx = fmaxf(mx, __shfl_xor(mx, 16, 64));
    mx = fmaxf(mx, __shfl_xor(mx, 32, 64));
    const float mn = fmaxf(m, mx);
    const float alpha = __expf(m - mn);
    m = mn;
    float srow = 0.f;
#pragma unroll
    for (int nt = 0; nt < 4; ++nt)
#pragma unroll
      for (int r = 0; r < 4; ++r) {
        const float e = __expf(s[nt][r] - mn);
        s[nt][r] = e;
        srow += e;
      }
    srow += __shfl_xor(srow, 16, 64);
    srow += __shfl_xor(srow, 32, 64);
    l = l * alpha + srow;
#pragma unroll
    for (int nt = 0; nt < 4; ++nt) o[nt] *= alpha;
#pragma unroll
    for (int nt = 0; nt < 4; ++nt) {
      const int kv = nt * 16 + lg * 4;
      int2 pv;
      pv.x = (int)pk2(s[nt][0], s[nt][1]);
      pv.y = (int)pk2(s[nt][2], s[nt][3]);
      *(int2*)(pw + l15 * 128 + (((kv >> 3) ^ (l15 & 7)) * 16) + (kv & 7) * 2) = pv;
    }
    asm volatile("" ::: "memory");
    bf16x8 pf[2];
#pragma unroll
    for (int kc = 0; kc < 2; ++kc)
      pf[kc] = *(const bf16x8*)(pw + l15 * 128 + (((kc * 4 + lg) ^ (l15 & 7)) * 16));
    __builtin_amdgcn_s_setprio(1);
#pragma unroll
    for (int kc = 0; kc < 2; ++kc)
#pragma unroll
      for (int nt = 0; nt < 4; ++nt) {
        const int row = nt * 16 + l15;
        bf16x8 vf = *(const bf16x8*)(Vc + row * 128 +
                                     (((kc * 4 + lg) ^ (row & 7)) * 16));
        o[nt] = __builtin_amdgcn_mfma_f32_16x16x32_bf16(vf, pf[kc], o[nt], 0, 0, 0);
      }
    __builtin_amdgcn_s_setprio(0);
  };

  stage(0, 0);
  int cur = 0;
#pragma unroll 1
  for (int kt = 0; kt <= q2t; ++kt) {
    __syncthreads();                        // buf[cur] staged; buf[cur^1] free
    if (kt < q2t) stage(kt + 1, cur ^ 1);   // loads fly under compute
    const char* Kc = (const char*)Kt[cur];
    const char* Vc = (const char*)Vt[cur];
    bf16x8 kf[2][4];
#pragma unroll
    for (int kc = 0; kc < 2; ++kc)
#pragma unroll
      for (int nt = 0; nt < 4; ++nt) {
        const int row = nt * 16 + l15;
        kf[kc][nt] = *(const bf16x8*)(Kc + row * 128 +
                                      (((kc * 4 + lg) ^ (row & 7)) * 16));
      }
    tile(qf2, kf, Vc, o2, m2s, l2s, kt == q2t);
    if (kt <= q1t) tile(qf1, kf, Vc, o1, m1s, l1s, kt == q1t);
    if (kt <= q0t) tile(qf0, kf, Vc, o0, m0s, l0s, kt == q0t);
    cur ^= 1;
  }

  // epilogue: lane holds O[q=l15][d=nt*16+lg*4+r]; ushort4 stores x3
  const int bq = bh / NHEAD, h = bh - bq * NHEAD;
  const float inv0 = 1.f / l0s, inv1 = 1.f / l1s, inv2 = 1.f / l2s;
#pragma unroll
  for (int nt = 0; nt < 4; ++nt) {
    ushort4 s0, s1, s2;
    s0.x = nbf(o0[nt][0] * inv0); s0.y = nbf(o0[nt][1] * inv0);
    s0.z = nbf(o0[nt][2] * inv0); s0.w = nbf(o0[nt][3] * inv0);
    s1.x = nbf(o1[nt][0] * inv1); s1.y = nbf(o1[nt][1] * inv1);
    s1.z = nbf(o1[nt][2] * inv1); s1.w = nbf(o1[nt][3] * inv1);
    s2.x = nbf(o2[nt][0] * inv2); s2.y = nbf(o2[nt][1] * inv2);
    s2.z = nbf(o2[nt][2] * inv2); s2.w = nbf(o2[nt][3] * inv2);
    const int col = h * HSZ + nt * 16 + lg * 4;
    *(ushort4*)(AO + ((size_t)(bq * SEQ + q0t * 64 + w * 16 + l15)) * EMBED + col) = s0;
    *(ushort4*)(AO + ((size_t)(bq * SEQ + q1t * 64 + w * 16 + l15)) * EMBED + col) = s1;
    *(ushort4*)(AO + ((size_t)(bq * SEQ + q2t * 64 + w * 16 + l15)) * EMBED + col) = s2;
  }
}

extern "C" void kernel_launch(void* const* d_in, const int* in_sizes, int n_in,
                              void* d_out, int out_size, void* d_ws, size_t ws_size,
                              hipStream_t stream) {
  const float* X  = (const float*)d_in[0];
  const float* Wq = (const float*)d_in[1];
  const float* Wk = (const float*)d_in[2];
  const float* Wv = (const float*)d_in[3];
  const float* Wo = (const float*)d_in[4];
  const float* bo = (const float*)d_in[5];
  float* out = (float*)d_out;

  const size_t NW = (size_t)EMBED * EMBED;   // 147456
  const size_t NX = (size_t)MROWS * EMBED;   // 9437184
  unsigned short* ws    = (unsigned short*)d_ws;
  unsigned short* Wqkvb = ws;                // 3*NW
  unsigned short* Wob   = Wqkvb + 3 * NW;    // NW (contiguous after Wqkvb)
  unsigned short* XbAO  = Wob + NW;          // NX: Xb (pre-attn) then AO
  unsigned short* Qb    = XbAO + NX;         // NX  [B,H,T,D]
  unsigned short* Kb    = Qb + NX;           // NX  [B,H,T,D]
  unsigned short* VTb   = Kb + NX;           // NX  [B,H,D,T] (transposed V)
  // total: 4*NW + 4*NX ushorts = 76.7 MB of d_ws

  cvtAll<<<(int)((NX + 4 * NW) / 4 / 256), 256, 0, stream>>>(
      X, Wq, Wk, Wv, Wo, Wqkvb, XbAO);

  gemm_bt<0><<<(MROWS / 128) * 9, 256, 0, stream>>>(
      XbAO, Wqkvb, Qb, Kb, VTb, nullptr, nullptr);

  attn<<<dim3(8, 96), 256, 0, stream>>>(Qb, Kb, VTb, XbAO);

  gemm_bt<1><<<(MROWS / 128) * 3, 256, 0, stream>>>(
      XbAO, Wob, nullptr, nullptr, nullptr, out, bo);
}